// Round 3
// baseline (578.472 us; speedup 1.0000x reference)
//
#include <hip/hip_runtime.h>

// RGCN, 3 layers. N=100000, E=1.6M, R=16, HID=64.
// Edges sorted by (dst,rel) via two-level LDS-bucketed sort (passes A/B).
// md = src | rel<<20 (one u32/edge).
// Layer kernel: 512-thread blocks (8 waves), 16 nodes/block.
// Phase 1 (waves 0-3): four 16-lane groups per wave, one node per group.
//   Each gather = dwordx2 (16 lanes x 8B = one 128B x-row) -> ONE load
//   instruction fetches FOUR edges' rows; md broadcast via ds_bpermute.
//   Branchless run-length mean (cndmask accumulate, flush-every-edge via
//   v_cvt_pk_bf16_f32, upfront LDS zero-fill). 8 loads x 4 lines = 32
//   lines in flight per wave. Avg (node,rel) segment len is ~1.3 so
//   branchy run-detection was ~34 VALU/edge; this is ~9.
// Phase 2 (all 8 waves): out = [H|x] @ Wcat via mfma_f32_16x16x32_bf16,
// K=1088 split in halves across wave pairs, partials reduced via LDS.

#define HID   64
#define NREL  16
#define KD    1088          // NREL*HID + HID (root x appended as extra K)
#define NPB   16            // nodes per block (= MFMA M)
#define LSTR  1104          // LDS row stride in us16 (1088 -> 1104, 32B-offset rows)

#define NBKT  1024          // coarse buckets (dst>>7); requires N <= 131072
#define BSH   7             // bucket shift: 128 nodes per bucket
#define FB    2048          // fine bins per bucket: 128 nodes * 16 rels
#define CAPB  4096          // LDS staging capacity (avg bucket = 2048 edges)
#define CHA   8192          // edges per coarse-pass block

typedef __attribute__((ext_vector_type(8))) short bf16x8;
typedef __attribute__((ext_vector_type(4))) float f32x4;
typedef unsigned short us16;
typedef unsigned int u32;

__device__ __forceinline__ us16 f2b(float f) {   // round-to-nearest-even
    union { float f; u32 i; } c; c.f = f;
    u32 x = c.i;
    return (us16)((x + 0x7FFFu + ((x >> 16) & 1u)) >> 16);
}

// ---------- setup: two-level bucket sort by (dst,rel) ----------

// Pass A0: coarse bucket counts via per-block LDS histogram.
__global__ __launch_bounds__(256) void bucket_count(const int* __restrict__ ei,
                                                    int* __restrict__ counts_b, int E) {
    __shared__ int h[NBKT];
    const int t = threadIdx.x;
    for (int i = t; i < NBKT; i += 256) h[i] = 0;
    __syncthreads();
    const int* dstp = ei + E;
    int start = blockIdx.x * CHA, end = min(start + CHA, E);
    for (int e4 = start + t * 4; e4 < end; e4 += 1024) {
        if (e4 + 3 < end) {
            int4 d = *(const int4*)(dstp + e4);
            atomicAdd(&h[d.x >> BSH], 1);
            atomicAdd(&h[d.y >> BSH], 1);
            atomicAdd(&h[d.z >> BSH], 1);
            atomicAdd(&h[d.w >> BSH], 1);
        } else {
            for (int e = e4; e < end; ++e) atomicAdd(&h[dstp[e] >> BSH], 1);
        }
    }
    __syncthreads();
    for (int i = t; i < NBKT; i += 256) {
        int v = h[i];
        if (v) atomicAdd(&counts_b[i], v);
    }
}

// Exclusive scan of the 1024 bucket counts (single block).
__global__ __launch_bounds__(NBKT) void scan_buckets(const int* __restrict__ counts_b,
                                                     int* __restrict__ bucket_base,
                                                     int* __restrict__ cursor_b,
                                                     int* __restrict__ row_ptr,
                                                     int N, int E) {
    __shared__ int s[NBKT];
    int t = threadIdx.x;
    int v = counts_b[t];
    s[t] = v; __syncthreads();
    for (int off = 1; off < NBKT; off <<= 1) {
        int tv = (t >= off) ? s[t - off] : 0;
        __syncthreads();
        s[t] += tv;
        __syncthreads();
    }
    int ex = s[t] - v;
    bucket_base[t] = ex;
    cursor_b[t] = ex;
    if (t == NBKT - 1) bucket_base[NBKT] = ex + v;
    if (t == 0) row_ptr[N] = E;
}

// Pass A1: place edges into coarse buckets; per-bucket runs are contiguous
// per block, so global writes coalesce. packed = src | rel<<17 | dstlow<<21.
__global__ __launch_bounds__(256) void bucket_place(const int* __restrict__ ei,
                                                    const int* __restrict__ et,
                                                    int* __restrict__ cursor_b,
                                                    u32* __restrict__ packed, int E) {
    __shared__ int cnt[NBKT];
    __shared__ int bse[NBKT];
    const int t = threadIdx.x;
    for (int i = t; i < NBKT; i += 256) cnt[i] = 0;
    __syncthreads();
    const int* dstp = ei + E;
    int start = blockIdx.x * CHA, end = min(start + CHA, E);
    for (int e4 = start + t * 4; e4 < end; e4 += 1024) {  // count
        if (e4 + 3 < end) {
            int4 d = *(const int4*)(dstp + e4);
            atomicAdd(&cnt[d.x >> BSH], 1);
            atomicAdd(&cnt[d.y >> BSH], 1);
            atomicAdd(&cnt[d.z >> BSH], 1);
            atomicAdd(&cnt[d.w >> BSH], 1);
        } else {
            for (int e = e4; e < end; ++e) atomicAdd(&cnt[dstp[e] >> BSH], 1);
        }
    }
    __syncthreads();
    for (int i = t; i < NBKT; i += 256) {                 // claim ranges
        int v = cnt[i];
        bse[i] = v ? atomicAdd(&cursor_b[i], v) : 0;
        cnt[i] = 0;
    }
    __syncthreads();
    #define PLACE1(sv, dv, tv)                                            \
        { int b_ = (dv) >> BSH;                                           \
          int r_ = atomicAdd(&cnt[b_], 1);                                \
          packed[bse[b_] + r_] = (u32)(sv) | ((u32)(tv) << 17)            \
                               | ((u32)((dv) & 127) << 21); }
    for (int e4 = start + t * 4; e4 < end; e4 += 1024) {  // place
        if (e4 + 3 < end) {
            int4 sv = *(const int4*)(ei + e4);
            int4 dv = *(const int4*)(dstp + e4);
            int4 tv = *(const int4*)(et + e4);
            PLACE1(sv.x, dv.x, tv.x);
            PLACE1(sv.y, dv.y, tv.y);
            PLACE1(sv.z, dv.z, tv.z);
            PLACE1(sv.w, dv.w, tv.w);
        } else {
            for (int e = e4; e < end; ++e) PLACE1(ei[e], dstp[e], et[e]);
        }
    }
    #undef PLACE1
}

// Pass B: fine sort within each bucket by (dstlow,rel); emits md (coalesced
// via LDS staging) and row_ptr (from the in-LDS exclusive scan).
__global__ __launch_bounds__(256) void bucket_sort(const u32* __restrict__ packed,
                                                   const int* __restrict__ bucket_base,
                                                   u32* __restrict__ md,
                                                   int* __restrict__ row_ptr, int N) {
    __shared__ int hist[FB];
    __shared__ int ss[256];
    __shared__ u32 outb[CAPB];
    const int b = blockIdx.x, t = threadIdx.x;
    const int base = bucket_base[b];
    const int cnt = bucket_base[b + 1] - base;

    for (int i = t; i < FB; i += 256) hist[i] = 0;
    __syncthreads();
    for (int i = t; i < cnt; i += 256) {                   // fine histogram
        u32 p = packed[base + i];
        int f = (int)(((p >> 21) & 127u) * 16u + ((p >> 17) & 15u));
        atomicAdd(&hist[f], 1);
    }
    __syncthreads();
    // exclusive scan of 2048 bins: 8 bins/thread + block scan of per-thread sums
    int loc[8], s = 0;
    #pragma unroll
    for (int j = 0; j < 8; ++j) { loc[j] = hist[t * 8 + j]; s += loc[j]; }
    ss[t] = s; __syncthreads();
    for (int off = 1; off < 256; off <<= 1) {
        int tv = (t >= off) ? ss[t - off] : 0;
        __syncthreads();
        ss[t] += tv;
        __syncthreads();
    }
    int run = ss[t] - s;
    #pragma unroll
    for (int j = 0; j < 8; ++j) { hist[t * 8 + j] = run; run += loc[j]; }
    __syncthreads();
    if (t < 128) {                                         // row_ptr from scan
        int node = b * 128 + t;
        if (node < N) row_ptr[node] = base + hist[t * 16];
    }
    __syncthreads();
    for (int i = t; i < cnt; i += 256) {                   // place into staging
        u32 p = packed[base + i];
        int f = (int)(((p >> 21) & 127u) * 16u + ((p >> 17) & 15u));
        int pos = atomicAdd(&hist[f], 1);
        u32 v = (p & 0x1FFFFu) | (((p >> 17) & 15u) << 20);
        if (pos < CAPB) outb[pos] = v;
        else            md[base + pos] = v;                // overflow fallback
    }
    __syncthreads();
    for (int i = t; i < cnt && i < CAPB; i += 256)         // coalesced stream-out
        md[base + i] = outb[i];
}

__global__ void convx_kernel(const float* __restrict__ x, us16* __restrict__ xb, int n4) {
    int i = blockIdx.x * 256 + threadIdx.x;    // n4 = N*HID/4
    if (i < n4) {
        float4 v = ((const float4*)x)[i];
        us16* o = xb + i * 4;
        o[0] = f2b(v.x); o[1] = f2b(v.y); o[2] = f2b(v.z); o[3] = f2b(v.w);
    }
}

// WcatT[l][h][k], k = r*64+d for k<1024, else root d = k-1024.  bf16.
__global__ void convw_kernel(const float* __restrict__ W, const float* __restrict__ Wroot,
                             us16* __restrict__ WcatT, int total, int L) {
    int i = blockIdx.x * 256 + threadIdx.x;    // total = L*HID*KD
    if (i < total) {
        int l = i / (HID * KD);
        int rem = i % (HID * KD);
        int h = rem / KD, k = rem % KD;
        float v;
        if (k < NREL * HID) {
            int r = k >> 6, d = k & 63;
            v = W[(((size_t)l * NREL + r) * HID + d) * HID + h];
        } else {
            int d = k - NREL * HID;
            v = Wroot[((size_t)l * HID + d) * HID + h];
        }
        WcatT[i] = f2b(v);
    }
}

// ---------- fused layer kernel ----------

// One edge-step for all 4 groups of a wave: branchless run-length mean.
// jj = position within window, jloc = position within the 8-batch.
__device__ __forceinline__ void step_e(u32 relp, int jloc, int jj, uint2 d, int rem,
                                       float& a0, float& a1, float& a2, float& a3,
                                       int& runlen, int& prev, us16* Hrow, int l16) {
    int rel = (int)((relp >> (4 * jloc)) & 15u);
    bool valid = jj < rem;
    bool keep = (rel == prev) || !valid;       // invalid steps: no-op rewrite
    u32 w0v = valid ? d.x : 0u;
    u32 w1v = valid ? d.y : 0u;
    float v0 = __uint_as_float(w0v << 16);
    float v1 = __uint_as_float(w0v & 0xFFFF0000u);
    float v2 = __uint_as_float(w1v << 16);
    float v3 = __uint_as_float(w1v & 0xFFFF0000u);
    a0 = (keep ? a0 : 0.f) + v0;
    a1 = (keep ? a1 : 0.f) + v1;
    a2 = (keep ? a2 : 0.f) + v2;
    a3 = (keep ? a3 : 0.f) + v3;
    runlen = (keep ? runlen : 0) + (valid ? 1 : 0);
    prev = valid ? rel : prev;
    float sc = __builtin_amdgcn_rcpf((float)runlen);
    float f0 = a0 * sc, f1 = a1 * sc, f2 = a2 * sc, f3 = a3 * sc;
    u32 p0, p1;
    asm("v_cvt_pk_bf16_f32 %0, %1, %2" : "=v"(p0) : "v"(f0), "v"(f1));
    asm("v_cvt_pk_bf16_f32 %0, %1, %2" : "=v"(p1) : "v"(f2), "v"(f3));
    uint2 pk; pk.x = p0; pk.y = p1;
    *(uint2*)(Hrow + (rel << 6) + (l16 << 2)) = pk;   // flush every edge
}

__global__ __launch_bounds__(512, 6) void layer_kernel(
        const us16* __restrict__ x_in,        // bf16 [N,64]
        const int*  __restrict__ row_ptr,     // [N+1]
        const u32*  __restrict__ md,          // sorted by (dst,rel): src | rel<<20
        const us16* __restrict__ WcatT,       // bf16 [64][1088] this layer
        const float* __restrict__ bias,       // fp32 [64] this layer
        us16* __restrict__ x_out,             // bf16 [N,64]  (if !last)
        float* __restrict__ out_f32,          // fp32 [N,64]  (if last)
        int flags, int N)                     // flags: 1=relu, 2=last
{
    __shared__ us16 H[NPB * LSTR];            // 35328 B
    __shared__ float P[NPB * HID];            // 4096 B partials; total 39424
    const int tid = threadIdx.x, wave = tid >> 6, lane = tid & 63;
    const int node0 = blockIdx.x * NPB;

    // ---- zero-prefill H (all 8 waves) ----
    {
        u32* hw = (u32*)H;
        for (int i = tid; i < NPB * LSTR / 2; i += 512) hw[i] = 0;
    }
    __syncthreads();

    // ---- phase 1 (waves 0-3): 4 nodes per wave, one per 16-lane group ----
    if (wave < 4) {
        const int g = lane >> 4, l16 = lane & 15;
        const int rowid = wave * 4 + g;
        const int ng = node0 + rowid;
        const bool nv = ng < N;
        const int rpv = row_ptr[nv ? ng : N];
        const int rpe = row_ptr[nv ? (ng + 1) : N];
        const int cnt = rpe - rpv;
        us16* Hrow = H + rowid * LSTR;
        const int pbase = (lane & 48) << 2;   // bpermute byte base of my group

        if (nv) {                             // root/x columns
            uint2 xv = *(const uint2*)(x_in + (size_t)ng * HID + l16 * 4);
            *(uint2*)(Hrow + NREL * HID + l16 * 4) = xv;
        }

        float a0 = 0.f, a1 = 0.f, a2 = 0.f, a3 = 0.f;
        int runlen = 0, prev = -1;

        for (int w0 = 0; w0 < cnt; w0 += 16) {            // divergent per group
            int rem = cnt - w0;                           // >= 1
            int mi = (rem - 1 < l16) ? (rem - 1) : l16;   // clamp tail
            u32 mdv = md[rpv + w0 + mi];                  // lane l16 holds edge w0+l16

            u32 rpA = 0, rpB = 0;
            uint2 dA[8], dB[8];
            #pragma unroll
            for (int j = 0; j < 8; ++j) {                 // batch A: issue 8x4 rows
                u32 m = (u32)__builtin_amdgcn_ds_bpermute(pbase + j * 4, (int)mdv);
                rpA |= ((m >> 20) & 15u) << (4 * j);
                dA[j] = *(const uint2*)(x_in + (size_t)(m & 0xFFFFFu) * HID + l16 * 4);
            }
            #pragma unroll
            for (int j = 0; j < 8; ++j) {                 // batch B: issue 8x4 rows
                u32 m = (u32)__builtin_amdgcn_ds_bpermute(pbase + (j + 8) * 4, (int)mdv);
                rpB |= ((m >> 20) & 15u) << (4 * j);
                dB[j] = *(const uint2*)(x_in + (size_t)(m & 0xFFFFFu) * HID + l16 * 4);
            }
            #pragma unroll
            for (int j = 0; j < 8; ++j)                   // consume A (B in flight)
                step_e(rpA, j, j, dA[j], rem, a0, a1, a2, a3, runlen, prev, Hrow, l16);
            #pragma unroll
            for (int j = 0; j < 8; ++j)                   // consume B
                step_e(rpB, j, j + 8, dB[j], rem, a0, a1, a2, a3, runlen, prev, Hrow, l16);
        }
    }
    __syncthreads();

    // ---- phase 2 (all 8 waves): [H|x] @ Wcat, K split in halves ----
    {
        const int n16 = lane & 15, quad = lane >> 4;
        const int kw = wave >> 2;             // which K-half
        const int wv = wave & 3;              // which 16-col group
        f32x4 acc = {0.f, 0.f, 0.f, 0.f};
        const us16* Abase = H + n16 * LSTR + quad * 8 + kw * (KD / 2);
        const us16* Bbase = WcatT + (size_t)(wv * 16 + n16) * KD + quad * 8 + kw * (KD / 2);
        #pragma unroll
        for (int ks = 0; ks < KD / 64; ++ks) {             // 17 steps, fully unrolled
            bf16x8 af = *(const bf16x8*)(Abase + ks * 32);
            bf16x8 bf = *(const bf16x8*)(Bbase + ks * 32);
            acc = __builtin_amdgcn_mfma_f32_16x16x32_bf16(af, bf, acc, 0, 0, 0);
        }

        int col = wv * 16 + n16;
        if (kw) {                                          // upper K-half -> LDS
            #pragma unroll
            for (int ri = 0; ri < 4; ++ri)
                P[(quad * 4 + ri) * HID + col] = acc[ri];
        }
        __syncthreads();
        if (!kw) {                                         // lower K-half: reduce+store
            float bv = bias[col];
            #pragma unroll
            for (int ri = 0; ri < 4; ++ri) {
                int nl = quad * 4 + ri, node = node0 + nl; // C/D: col=lane&15, row=quad*4+ri
                if (node < N) {
                    float v = acc[ri] + P[nl * HID + col] + bv;
                    if (flags & 1) v = fmaxf(v, 0.f);
                    if (flags & 2) out_f32[node * HID + col] = v;
                    else           x_out [node * HID + col] = f2b(v);
                }
            }
        }
    }
}

// ---------- host ----------

extern "C" void kernel_launch(void* const* d_in, const int* in_sizes, int n_in,
                              void* d_out, int out_size, void* d_ws, size_t ws_size,
                              hipStream_t stream) {
    const int*   edge_index = (const int*)  d_in[0];
    const int*   edge_type  = (const int*)  d_in[1];
    const float* node_emb   = (const float*)d_in[2];
    const float* W          = (const float*)d_in[3];
    const float* Wroot      = (const float*)d_in[4];
    const float* bias       = (const float*)d_in[5];
    float* out = (float*)d_out;

    const int E = in_sizes[1];
    const int N = in_sizes[2] / HID;
    const int L = in_sizes[5] / HID;

    char* p = (char*)d_ws;
    size_t off = 0;
    auto carve = [&](size_t bytes) {
        void* q = p + off;
        off = (off + bytes + 255) & ~(size_t)255;
        return q;
    };
    int*   counts_b    = (int*)  carve((size_t)NBKT * 4);
    int*   bucket_base = (int*)  carve((size_t)(NBKT + 1) * 4);
    int*   cursor_b    = (int*)  carve((size_t)NBKT * 4);
    int*   row_ptr     = (int*)  carve((size_t)(N + 1) * 4);
    u32*   packed      = (u32*)  carve((size_t)E * 4);
    u32*   md          = (u32*)  carve((size_t)E * 4);
    us16*  xb0         = (us16*) carve((size_t)N * HID * 2);
    us16*  xb1         = (us16*) carve((size_t)N * HID * 2);
    us16*  WcatT       = (us16*) carve((size_t)L * HID * KD * 2);
    (void)ws_size; (void)n_in; (void)out_size;

    hipMemsetAsync(counts_b, 0, (size_t)NBKT * 4, stream);

    const int nblkA = (E + CHA - 1) / CHA;
    bucket_count<<<nblkA, 256, 0, stream>>>(edge_index, counts_b, E);
    scan_buckets<<<1, NBKT, 0, stream>>>(counts_b, bucket_base, cursor_b, row_ptr, N, E);
    bucket_place<<<nblkA, 256, 0, stream>>>(edge_index, edge_type, cursor_b, packed, E);
    bucket_sort<<<(N + 127) / 128, 256, 0, stream>>>(packed, bucket_base, md, row_ptr, N);

    convx_kernel<<<(N * HID / 4 + 255) / 256, 256, 0, stream>>>(node_emb, xb0, N * HID / 4);
    int wtot = L * HID * KD;
    convw_kernel<<<(wtot + 255) / 256, 256, 0, stream>>>(W, Wroot, WcatT, wtot, L);

    int gl = (N + NPB - 1) / NPB;
    us16* xin = xb0;
    us16* xother = xb1;
    for (int l = 0; l < L; ++l) {
        int last = (l == L - 1);
        int flags = (last ? 2 : 1);
        layer_kernel<<<gl, 512, 0, stream>>>(
            xin, row_ptr, md,
            WcatT + (size_t)l * HID * KD, bias + (size_t)l * HID,
            last ? nullptr : xother, last ? out : nullptr,
            flags, N);
        us16* t = xin; xin = xother; xother = t;
    }
}